// Round 3
// baseline (186.521 us; speedup 1.0000x reference)
//
#include <hip/hip_runtime.h>
#include <stdint.h>

// Problem dims (fixed by the reference)
#define NB   8192
#define NZ   10
#define CIN  512
#define COUT 512
#define MM   3
#define ALPHA 0.04419417382415922f   // 1/sqrt(512)

#define ROWS_TOTAL (NB * MM)         // 24576 effective GEMM rows (node,d)
#define BM 128
#define BN 128
#define BK 32
#define KITERS (CIN / BK)            // 16
#define MAX_MT (ROWS_TOTAL / BM + NZ) // 202: sum_z ceil(3*n_z/128)

typedef short bf16x8 __attribute__((ext_vector_type(8)));
typedef float f32x4  __attribute__((ext_vector_type(4)));

__device__ __forceinline__ uint16_t f2bf(float f) {
    union { float f; uint32_t i; } v; v.f = f;
    uint32_t x = v.i;
    x += 0x7fffu + ((x >> 16) & 1u);   // RNE
    return (uint16_t)(x >> 16);
}
__device__ __forceinline__ uint32_t pack2(float a, float b) {
    return (uint32_t)f2bf(a) | ((uint32_t)f2bf(b) << 16);
}
// async global->LDS, 16B per lane. LDS dest = wave-uniform base + lane*16.
__device__ __forceinline__ void async16(const ushort* g, ushort* l) {
    __builtin_amdgcn_global_load_lds((const uint32_t*)g, (uint32_t*)l, 16, 0, 0);
}

// ---------------- K0: decode one-hot + ballot histogram ----------------
__global__ __launch_bounds__(256)
void decode_count(const float* __restrict__ attrs, int* __restrict__ species,
                  int* __restrict__ cnt) {
    const int b = blockIdx.x * 256 + threadIdx.x;
    const float* a = attrs + (size_t)b * NZ;
    int s = 0;
    #pragma unroll
    for (int z = 0; z < NZ; z++) if (a[z] > 0.5f) s = z;
    species[b] = s;
    const int lane = threadIdx.x & 63;
    #pragma unroll
    for (int z = 0; z < NZ; z++) {
        unsigned long long m = __ballot(s == z);
        if (lane == 0 && m) atomicAdd(&cnt[z], __popcll(m));
    }
}

// ---------------- K1: tiny serial scan ----------------
__global__ void scan_kernel(const int* __restrict__ cnt, int* __restrict__ offsets,
                            int* __restrict__ tile_offsets, int* __restrict__ cur) {
    if (threadIdx.x == 0) {
        int off = 0, toff = 0;
        for (int z = 0; z < NZ; z++) {
            offsets[z] = off; tile_offsets[z] = toff; cur[z] = off;
            off  += cnt[z];
            toff += (3 * cnt[z] + BM - 1) / BM;
        }
        offsets[NZ] = off; tile_offsets[NZ] = toff;
    }
}

// ---------------- K2: ballot-based placement (any order within species) ----
__global__ __launch_bounds__(256)
void place_kernel(const int* __restrict__ species, int* __restrict__ cur,
                  int* __restrict__ sorted) {
    const int b = blockIdx.x * 256 + threadIdx.x;
    const int s = species[b];
    const int lane = threadIdx.x & 63;
    #pragma unroll
    for (int z = 0; z < NZ; z++) {
        unsigned long long m = __ballot(s == z);
        if (s == z) {
            int leader = __ffsll((unsigned long long)m) - 1;
            int rank = __popcll(m & ((1ull << lane) - 1ull));
            int base = 0;
            if (lane == leader) base = atomicAdd(&cur[z], __popcll(m));
            base = __shfl(base, leader);
            sorted[base + rank] = b;
        }
    }
}

// ---------------- K3a: pack t -> tt bf16, sorted order, d-major rows -------
// tt[3*p + d][c] = bf16(t[sorted[p]][c][d]) : each row contiguous in k=c.
__global__ __launch_bounds__(256)
void pack_t(const float* __restrict__ t, const int* __restrict__ sorted,
            ushort* __restrict__ tt) {
    const int w = threadIdx.x >> 6, L = threadIdx.x & 63;
    const int p = blockIdx.x * 4 + w;          // sorted position, one wave/node
    const int node = sorted[p];
    const float4* src = (const float4*)(t + (size_t)node * (CIN * MM) + L * 24);
    float4 f[6];
    #pragma unroll
    for (int i = 0; i < 6; i++) f[i] = src[i];
    const float* v = (const float*)f;          // v[c_local*3 + d], c_local in [0,8)
    #pragma unroll
    for (int d = 0; d < MM; d++) {
        uint4 o;
        o.x = pack2(v[d],      v[3 + d]);
        o.y = pack2(v[6 + d],  v[9 + d]);
        o.z = pack2(v[12 + d], v[15 + d]);
        o.w = pack2(v[18 + d], v[21 + d]);
        *(uint4*)&tt[(size_t)(3 * p + d) * CIN + L * 8] = o;
    }
}

// ---------------- K3b: pack W -> wt bf16 (same layout) ----------------
__global__ __launch_bounds__(256)
void pack_w(const float* __restrict__ w, ushort* __restrict__ wt) {
    const int i = (blockIdx.x * 256 + threadIdx.x) * 8;
    float4 a = *(const float4*)(w + i);
    float4 b = *(const float4*)(w + i + 4);
    uint4 o;
    o.x = pack2(a.x, a.y); o.y = pack2(a.z, a.w);
    o.z = pack2(b.x, b.y); o.w = pack2(b.z, b.w);
    *(uint4*)(wt + i) = o;
}

// ---------------- K4: 128x128 MFMA GEMM over species segments ----------------
// D[row=(node,d)][col=C] = sum_c tt[row][c] * wt[z*512+C][c]
__global__ __launch_bounds__(256)
void gemm_kernel(const ushort* __restrict__ tt, const ushort* __restrict__ wt,
                 const int* __restrict__ sorted, const int* __restrict__ offsets,
                 const int* __restrict__ tile_offsets, float* __restrict__ out) {
    __shared__ ushort As[BM][BK];   // 8 KB, unpadded: global_load_lds layout
    __shared__ ushort Bs[BN][BK];   // 8 KB

    const int tz = blockIdx.x;
    if (tz >= tile_offsets[NZ]) return;          // uniform exit before barriers
    int z = 0;
    #pragma unroll
    for (int i = 1; i < NZ; i++) if (tile_offsets[i] <= tz) z = i;

    const int row_base = 3 * offsets[z] + (tz - tile_offsets[z]) * BM;
    const int row_end  = 3 * offsets[z + 1];
    const int Cbase    = blockIdx.y * BN;

    const int tid = threadIdx.x;
    const int w = tid >> 6, L = tid & 63;

    // staging: wave w covers A rows [w*32, w*32+32) in two 16-row instrs
    const int lrow = L >> 2;            // 0..15
    const int lk   = (L & 3) * 8;       // bf16 elems: 0,8,16,24
    const ushort* gA = tt + (size_t)(row_base + w * 32 + lrow) * CIN + lk;
    const ushort* gB = wt + ((size_t)z * COUT + Cbase + w * 32 + lrow) * CIN + lk;
    ushort* lA0 = &As[w * 32][0];
    ushort* lA1 = &As[w * 32 + 16][0];
    ushort* lB0 = &Bs[w * 32][0];
    ushort* lB1 = &Bs[w * 32 + 16][0];

    // compute: 2x2 wave grid, each wave 64x64 = 4x4 mfma tiles
    const int wm = w & 1, wn = w >> 1;
    const int q = L >> 4, mr = L & 15;

    f32x4 acc[4][4];
    #pragma unroll
    for (int i = 0; i < 4; i++)
        #pragma unroll
        for (int j = 0; j < 4; j++) acc[i][j] = (f32x4){0.f, 0.f, 0.f, 0.f};

    for (int kt = 0; kt < KITERS; kt++) {
        const int ko = kt * BK;
        async16(gA + ko, lA0);
        async16(gA + (size_t)16 * CIN + ko, lA1);
        async16(gB + ko, lB0);
        async16(gB + (size_t)16 * CIN + ko, lB1);
        __syncthreads();   // drains vmcnt: LDS tiles complete

        bf16x8 af[4], bf[4];
        #pragma unroll
        for (int am = 0; am < 4; am++)
            af[am] = *(const bf16x8*)&As[wm * 64 + am * 16 + mr][q * 8];
        #pragma unroll
        for (int bn = 0; bn < 4; bn++)
            bf[bn] = *(const bf16x8*)&Bs[wn * 64 + bn * 16 + mr][q * 8];
        #pragma unroll
        for (int am = 0; am < 4; am++)
            #pragma unroll
            for (int bn = 0; bn < 4; bn++)
                acc[am][bn] = __builtin_amdgcn_mfma_f32_16x16x32_bf16(
                    af[am], bf[bn], acc[am][bn], 0, 0, 0);
        __syncthreads();
    }

    // epilogue: row -> (pos=row/3, d=row%3, node=sorted[pos]); out[node][C][d]
    #pragma unroll
    for (int am = 0; am < 4; am++) {
        #pragma unroll
        for (int r = 0; r < 4; r++) {
            const int Rg = row_base + wm * 64 + am * 16 + q * 4 + r;
            if (Rg < row_end) {
                const int pos = Rg / 3;
                const int d = Rg - 3 * pos;
                const int node = sorted[pos];
                float* o = out + (size_t)node * (COUT * MM) + d;
                #pragma unroll
                for (int bn = 0; bn < 4; bn++) {
                    const int Cg = Cbase + wn * 64 + bn * 16 + mr;
                    o[(size_t)Cg * 3] = ALPHA * acc[am][bn][r];
                }
            }
        }
    }
}

extern "C" void kernel_launch(void* const* d_in, const int* in_sizes, int n_in,
                              void* d_out, int out_size, void* d_ws, size_t ws_size,
                              hipStream_t stream) {
    const float* t     = (const float*)d_in[0];   // [B, IN, 3]  fp32
    const float* attrs = (const float*)d_in[1];   // [B, Z]      fp32 one-hot
    const float* w     = (const float*)d_in[2];   // [Z, OUT, IN] fp32
    float* out = (float*)d_out;                   // [B, OUT, 3] fp32

    // workspace layout
    uint8_t* ws = (uint8_t*)d_ws;
    int* species      = (int*)ws;                        ws += NB * 4;
    int* sorted       = (int*)ws;                        ws += NB * 4;
    int* cnt          = (int*)ws;                        ws += 16 * 4;
    int* offsets      = (int*)ws;                        ws += 16 * 4;
    int* tile_offsets = (int*)ws;                        ws += 16 * 4;
    int* cur          = (int*)ws;                        ws += 16 * 4;
    ws = (uint8_t*)(((uintptr_t)ws + 255) & ~(uintptr_t)255);
    ushort* wt = (ushort*)ws;                            ws += (size_t)NZ * COUT * CIN * 2;
    ushort* tt = (ushort*)ws;   // (ROWS_TOTAL + BM) rows of CIN bf16

    hipMemsetAsync(cnt, 0, 16 * 4, stream);
    hipLaunchKernelGGL(decode_count, dim3(NB / 256), dim3(256), 0, stream,
                       attrs, species, cnt);
    hipLaunchKernelGGL(scan_kernel, dim3(1), dim3(64), 0, stream,
                       cnt, offsets, tile_offsets, cur);
    hipLaunchKernelGGL(place_kernel, dim3(NB / 256), dim3(256), 0, stream,
                       species, cur, sorted);
    hipLaunchKernelGGL(pack_t, dim3(NB / 4), dim3(256), 0, stream,
                       t, sorted, tt);
    hipLaunchKernelGGL(pack_w, dim3((NZ * COUT * CIN) / (256 * 8)), dim3(256), 0, stream,
                       w, wt);
    hipLaunchKernelGGL(gemm_kernel, dim3(MAX_MT, COUT / BN), dim3(256), 0, stream,
                       tt, wt, sorted, offsets, tile_offsets, out);
}

// Round 5
// 159.650 us; speedup vs baseline: 1.1683x; 1.1683x over previous
//
#include <hip/hip_runtime.h>
#include <stdint.h>

// Problem dims (fixed by the reference)
#define NB   8192
#define NZ   10
#define CIN  512
#define COUT 512
#define MM   3
#define ALPHA 0.04419417382415922f   // 1/sqrt(512)

#define ROWS_TOTAL (NB * MM)          // 24576 GEMM rows (pos,d) d-fastest
#define BM 128
#define BN 64
#define BK 32
#define KITERS (CIN / BK)             // 16
#define MAX_MT (ROWS_TOTAL / BM + NZ) // 202
#define NGRP 32                       // histogram groups of 256 nodes

typedef short bf16x8 __attribute__((ext_vector_type(8)));
typedef float f32x4  __attribute__((ext_vector_type(4)));

__device__ __forceinline__ uint16_t f2bf(float f) {
    union { float f; uint32_t i; } v; v.f = f;
    uint32_t x = v.i;
    x += 0x7fffu + ((x >> 16) & 1u);   // RNE
    return (uint16_t)(x >> 16);
}
__device__ __forceinline__ uint32_t pack2(float a, float b) {
    return (uint32_t)f2bf(a) | ((uint32_t)f2bf(b) << 16);
}
__device__ __forceinline__ void async16(const ushort* g, ushort* l) {
    __builtin_amdgcn_global_load_lds((const uint32_t*)g, (uint32_t*)l, 16, 0, 0);
}

// ---- K0: blocks 0..31 decode species + per-group histogram;
//          blocks 32..1311 pack W fp32->bf16 -----------------------------
__global__ __launch_bounds__(256)
void prep_kernel(const float* __restrict__ attrs, const float* __restrict__ w,
                 int* __restrict__ species, int* __restrict__ hist,
                 ushort* __restrict__ wt) {
    const int tid = threadIdx.x;
    if (blockIdx.x >= NGRP) {
        // ---- pack_w: 1280 blocks x 256 threads x 8 elems
        const size_t i = ((size_t)(blockIdx.x - NGRP) * 256 + tid) * 8;
        float4 a = *(const float4*)(w + i);
        float4 b = *(const float4*)(w + i + 4);
        uint4 o;
        o.x = pack2(a.x, a.y); o.y = pack2(a.z, a.w);
        o.z = pack2(b.x, b.y); o.w = pack2(b.z, b.w);
        *(uint4*)(wt + i) = o;
        return;
    }
    // ---- decode + histogram (ballot, no atomics)
    __shared__ int wc[4][NZ];
    const int b = blockIdx.x * 256 + tid;
    const float* a = attrs + (size_t)b * NZ;
    int s = 0;
    #pragma unroll
    for (int z = 0; z < NZ; z++) if (a[z] > 0.5f) s = z;
    species[b] = s;
    const int wv = tid >> 6, lane = tid & 63;
    #pragma unroll
    for (int z = 0; z < NZ; z++) {
        unsigned long long m = __ballot(s == z);
        if (lane == 0) wc[wv][z] = __popcll(m);
    }
    __syncthreads();
    if (tid < NZ) {
        hist[blockIdx.x * NZ + tid] = wc[0][tid] + wc[1][tid] + wc[2][tid] + wc[3][tid];
    }
}

// ---- K1: place (deterministic, atomic-free). 32 blocks x 256.
// Each block redundantly scans hist -> per-species base for its group.
// Block 0 publishes offsets / tile_offsets for the gemm.
__global__ __launch_bounds__(256)
void place_kernel(const int* __restrict__ species, const int* __restrict__ hist,
                  int* __restrict__ sorted, int* __restrict__ offsets,
                  int* __restrict__ tile_offsets) {
    __shared__ int lhist[NGRP][NZ];
    __shared__ int loff[NZ + 1], ltoff[NZ + 1];
    __shared__ int pb[NZ];
    __shared__ int wc[4][NZ];
    const int tid = threadIdx.x, g = blockIdx.x;

    // FIX (R4 crash): NGRP*NZ = 320 > 256 — must strided-load, the tail 64
    // entries were previously uninitialized -> garbage scatter -> page fault.
    for (int i = tid; i < NGRP * NZ; i += 256) ((int*)lhist)[i] = hist[i];
    __syncthreads();
    if (tid == 0) {
        int off = 0, toff = 0;
        for (int z = 0; z < NZ; z++) {
            int tot = 0;
            for (int gg = 0; gg < NGRP; gg++) tot += lhist[gg][z];
            loff[z] = off; ltoff[z] = toff;
            off += tot;
            toff += (3 * tot + BM - 1) / BM;
        }
        loff[NZ] = off; ltoff[NZ] = toff;
    }
    __syncthreads();
    if (tid < NZ) {
        int base = loff[tid];
        for (int gg = 0; gg < g; gg++) base += lhist[gg][tid];
        pb[tid] = base;
    }
    if (g == 0 && tid < NZ + 1) {
        offsets[tid] = loff[tid];
        tile_offsets[tid] = ltoff[tid];
    }
    const int b = g * 256 + tid;
    const int s = species[b];
    const int wv = tid >> 6, lane = tid & 63;
    unsigned long long mymask = 0;
    #pragma unroll
    for (int z = 0; z < NZ; z++) {
        unsigned long long m = __ballot(s == z);
        if (lane == 0) wc[wv][z] = __popcll(m);
        if (s == z) mymask = m;
    }
    __syncthreads();
    int rank = __popcll(mymask & ((1ull << lane) - 1ull));
    #pragma unroll
    for (int w2 = 0; w2 < 4; w2++) if (w2 < wv) rank += wc[w2][s];
    sorted[pb[s] + rank] = b;
}

// ---- K2: pack t -> tt bf16, sorted order, d-major rows --------------------
// tt[3*p + d][c] = bf16(t[sorted[p]][c][d])
__global__ __launch_bounds__(256)
void pack_t(const float* __restrict__ t, const int* __restrict__ sorted,
            ushort* __restrict__ tt) {
    const int w = threadIdx.x >> 6, L = threadIdx.x & 63;
    const int p = blockIdx.x * 4 + w;
    const int node = sorted[p];
    const float4* src = (const float4*)(t + (size_t)node * (CIN * MM) + L * 24);
    float4 f[6];
    #pragma unroll
    for (int i = 0; i < 6; i++) f[i] = src[i];
    const float* v = (const float*)f;          // v[c_local*3 + d]
    #pragma unroll
    for (int d = 0; d < MM; d++) {
        uint4 o;
        o.x = pack2(v[d],      v[3 + d]);
        o.y = pack2(v[6 + d],  v[9 + d]);
        o.z = pack2(v[12 + d], v[15 + d]);
        o.w = pack2(v[18 + d], v[21 + d]);
        *(uint4*)&tt[(size_t)(3 * p + d) * CIN + L * 8] = o;
    }
}

// ---- K3: 128x64 MFMA GEMM over species segments ---------------------------
__global__ __launch_bounds__(256)
void gemm_kernel(const ushort* __restrict__ tt, const ushort* __restrict__ wt,
                 const int* __restrict__ sorted, const int* __restrict__ offsets,
                 const int* __restrict__ tile_offsets, float* __restrict__ out) {
    __shared__ ushort As[BM][BK];   // 8 KB
    __shared__ ushort Bs[BN][BK];   // 4 KB
    __shared__ int spos[48];        // sorted[] slice for epilogue

    const int tz = blockIdx.x;
    if (tz >= tile_offsets[NZ]) return;
    int z = 0;
    #pragma unroll
    for (int i = 1; i < NZ; i++) if (tile_offsets[i] <= tz) z = i;

    const int row_base = 3 * offsets[z] + (tz - tile_offsets[z]) * BM;
    const int row_end  = 3 * offsets[z + 1];
    const int pos0     = row_base / 3;
    const int Cbase    = blockIdx.y * BN;

    const int tid = threadIdx.x;
    const int w = tid >> 6, L = tid & 63;

    if (tid < 48) spos[tid] = sorted[min(pos0 + tid, NB - 1)];

    // staging: wave w -> A rows [w*32, w*32+32) (two instrs), B rows [w*16, w*16+16)
    const int lrow = L >> 2;            // 0..15
    const int lk   = (L & 3) * 8;
    const ushort* gA = tt + (size_t)(row_base + w * 32 + lrow) * CIN + lk;
    const ushort* gB = wt + ((size_t)z * COUT + Cbase + w * 16 + lrow) * CIN + lk;
    ushort* lA0 = &As[w * 32][0];
    ushort* lA1 = &As[w * 32 + 16][0];
    ushort* lB0 = &Bs[w * 16][0];

    // compute: 2x2 wave grid; wave tile 64 rows x 32 cols
    const int wm = w & 1, wn = w >> 1;
    const int q = L >> 4, mr = L & 15;

    f32x4 acc[4][2];
    #pragma unroll
    for (int i = 0; i < 4; i++)
        #pragma unroll
        for (int j = 0; j < 2; j++) acc[i][j] = (f32x4){0.f, 0.f, 0.f, 0.f};

    for (int kt = 0; kt < KITERS; kt++) {
        const int ko = kt * BK;
        async16(gA + ko, lA0);
        async16(gA + (size_t)16 * CIN + ko, lA1);
        async16(gB + ko, lB0);
        __syncthreads();

        bf16x8 af[4], bf[2];
        #pragma unroll
        for (int am = 0; am < 4; am++)
            af[am] = *(const bf16x8*)&As[wm * 64 + am * 16 + mr][q * 8];
        #pragma unroll
        for (int bn = 0; bn < 2; bn++)
            bf[bn] = *(const bf16x8*)&Bs[wn * 32 + bn * 16 + mr][q * 8];
        #pragma unroll
        for (int am = 0; am < 4; am++)
            #pragma unroll
            for (int bn = 0; bn < 2; bn++)
                acc[am][bn] = __builtin_amdgcn_mfma_f32_16x16x32_bf16(
                    af[am], bf[bn], acc[am][bn], 0, 0, 0);
        __syncthreads();
    }

    // epilogue: row -> (pos, d); out[node][C][d]
    #pragma unroll
    for (int am = 0; am < 4; am++) {
        #pragma unroll
        for (int r = 0; r < 4; r++) {
            const int Rg = row_base + wm * 64 + am * 16 + q * 4 + r;
            if (Rg < row_end) {
                const int pos = Rg / 3;
                const int d = Rg - 3 * pos;
                const int node = spos[pos - pos0];
                float* o = out + (size_t)node * (COUT * MM) + d;
                #pragma unroll
                for (int bn = 0; bn < 2; bn++) {
                    const int Cg = Cbase + wn * 32 + bn * 16 + mr;
                    o[(size_t)Cg * 3] = ALPHA * acc[am][bn][r];
                }
            }
        }
    }
}

extern "C" void kernel_launch(void* const* d_in, const int* in_sizes, int n_in,
                              void* d_out, int out_size, void* d_ws, size_t ws_size,
                              hipStream_t stream) {
    const float* t     = (const float*)d_in[0];   // [B, IN, 3]  fp32
    const float* attrs = (const float*)d_in[1];   // [B, Z]      fp32 one-hot
    const float* w     = (const float*)d_in[2];   // [Z, OUT, IN] fp32
    float* out = (float*)d_out;                   // [B, OUT, 3] fp32

    uint8_t* ws = (uint8_t*)d_ws;
    int* species      = (int*)ws;                  ws += NB * 4;
    int* sorted       = (int*)ws;                  ws += NB * 4;
    int* hist         = (int*)ws;                  ws += NGRP * NZ * 4;
    int* offsets      = (int*)ws;                  ws += 16 * 4;
    int* tile_offsets = (int*)ws;                  ws += 16 * 4;
    ws = (uint8_t*)(((uintptr_t)ws + 255) & ~(uintptr_t)255);
    ushort* wt = (ushort*)ws;                      ws += (size_t)NZ * COUT * CIN * 2;
    ushort* tt = (ushort*)ws;                      // ROWS_TOTAL+BM rows x CIN bf16

    // K0: 32 decode blocks + 1280 pack_w blocks
    hipLaunchKernelGGL(prep_kernel, dim3(NGRP + (NZ * COUT * CIN) / 2048), dim3(256),
                       0, stream, attrs, w, species, hist, wt);
    // K1: place (scan folded in, atomic-free)
    hipLaunchKernelGGL(place_kernel, dim3(NGRP), dim3(256), 0, stream,
                       species, hist, sorted, offsets, tile_offsets);
    // K2: pack t in sorted order
    hipLaunchKernelGGL(pack_t, dim3(NB / 4), dim3(256), 0, stream, t, sorted, tt);
    // K3: GEMM
    hipLaunchKernelGGL(gemm_kernel, dim3(MAX_MT, COUT / BN), dim3(256), 0, stream,
                       tt, wt, sorted, offsets, tile_offsets, out);
}